// Round 8
// baseline (330.225 us; speedup 1.0000x reference)
//
#include <hip/hip_runtime.h>
#include <hip/hip_bf16.h>
#include <math.h>

// SlotAttention on MI355X.
// Factorizations:
//   k,v never materialized:  qk = LN(slots) @ (Wq^T Wk);  logits = x·qk
//   updates feeds only the GRU input GEMM:  gi = uxr @ (wih·Wv)^T  (M precomputed)
//   token-normalization 1/(colsum+eps) commutes out of the P^T@X accumulation.
// R8: k3 reshaped for occupancy (R7 showed 26% occ / 2 TB/s / nothing busy ->
//     load-concurrency bound). 32-row blocks (grid 4096), LDS ~20KB -> 8
//     blocks/CU; GEMM1 on 2 waves; ux partials in bf16, LDS-bounced for
//     coalesced stores. Slot chain unchanged (proven).

#define EPS_ 1e-8f
#define LNEPS_ 1e-5f
// Xs element-index swizzle (R6, verified): spreads GEMM2's row-gather onto
// disjoint bank octets. Granularity 8 shorts -> b128 reads intact.
#define XSW(r) ((((r)&7)<<3) ^ ((((r)>>3)&3)<<4))

typedef __attribute__((ext_vector_type(8))) short bf16x8;
typedef __attribute__((ext_vector_type(4))) float f32x4;
typedef __attribute__((ext_vector_type(4))) short s16x4;

static __device__ __forceinline__ short f2bf(float f) {
  __hip_bfloat16 h = __float2bfloat16(f);
  union { __hip_bfloat16 h; short s; } u; u.h = h; return u.s;
}
static __device__ __forceinline__ float bf2f(short s) {
  union { float f; unsigned u; } x; x.u = ((unsigned)(unsigned short)s) << 16; return x.f;
}
static __device__ __forceinline__ float4 ld4(const float* p){ return *(const float4*)p; }

// ---------------- prep: MT = Wq^T Wk, M = wih@Wv, bf16 casts ----------------
__global__ __launch_bounds__(256) void k_prep(
    const float* __restrict__ Wq, const float* __restrict__ Wk,
    const float* __restrict__ wih, const float* __restrict__ Wv,
    const float* __restrict__ whh, const float* __restrict__ w1, const float* __restrict__ w2,
    short* __restrict__ MTb, short* __restrict__ Mb, short* __restrict__ whhb,
    short* __restrict__ w1b, short* __restrict__ w2b) {
  int blk = blockIdx.x, t = threadIdx.x;
  if (blk < 64) {                 // MT[e][f] = sum_d Wq[d][f]*Wk[d][e]
    int e0 = blk*4;
    float a0=0,a1=0,a2=0,a3=0;
    for (int d=0; d<256; d++) {
      float qv = Wq[d*256 + t];
      a0 += qv*Wk[d*256+e0];   a1 += qv*Wk[d*256+e0+1];
      a2 += qv*Wk[d*256+e0+2]; a3 += qv*Wk[d*256+e0+3];
    }
    MTb[(e0  )*256+t]=f2bf(a0); MTb[(e0+1)*256+t]=f2bf(a1);
    MTb[(e0+2)*256+t]=f2bf(a2); MTb[(e0+3)*256+t]=f2bf(a3);
  } else if (blk < 256) {         // M[n][e] = sum_d wih[n][d]*Wv[d][e]
    int n0 = (blk-64)*4;
    float a0=0,a1=0,a2=0,a3=0;
    for (int d=0; d<256; d++) {
      float vv = Wv[d*256 + t];
      a0 += wih[(n0  )*256+d]*vv; a1 += wih[(n0+1)*256+d]*vv;
      a2 += wih[(n0+2)*256+d]*vv; a3 += wih[(n0+3)*256+d]*vv;
    }
    Mb[(size_t)(n0  )*256+t]=f2bf(a0); Mb[(size_t)(n0+1)*256+t]=f2bf(a1);
    Mb[(size_t)(n0+2)*256+t]=f2bf(a2); Mb[(size_t)(n0+3)*256+t]=f2bf(a3);
  } else {                        // casts: whh 49152, w1 32768, w2 32768 float4s
    int c = (blk-256)*256 + t;
    const float* src; short* dst;
    if (c < 49152) { src=whh; dst=whhb; }
    else if ((c-=49152) < 32768) { src=w1; dst=w1b; }
    else { c-=32768; src=w2; dst=w2b; }
    float4 v = ld4(src + (size_t)c*4);
    short4 o; o.x=f2bf(v.x); o.y=f2bf(v.y); o.z=f2bf(v.z); o.w=f2bf(v.w);
    *(short4*)(dst + (size_t)c*4) = o;
  }
}

// ---------------- fused attention pass (+optional LN-of-inputs) ----------------
// grid = B*128 = 4096 blocks (ONE 32-token-row tile each), 256 threads = 4 waves.
// GEMM1+softmax on waves 0,1 (2 row-tiles); GEMM2 (K=32) on all 4 waves.
template<int LNIN, int WATTN>
__global__ __launch_bounds__(256, 6) void k3(
    const float* __restrict__ inputs, const float* __restrict__ lnw, const float* __restrict__ lnb,
    short* __restrict__ xbf, const short* __restrict__ qk, const float* __restrict__ twg,
    short* __restrict__ ux_part, float* __restrict__ colsum_part, float* __restrict__ attn_un) {
  __shared__ __align__(16) short Xs[32*256];   // 16KB: [row][elem ^ XSW(row)]
  __shared__ __align__(16) short Pt[16*40];    // P^T [s][32 rows], stride 40
  __shared__ float tws[32];
  __shared__ float cs[16];
  __shared__ float lnwb[512];
  const int t = threadIdx.x;
  const int b = blockIdx.x >> 7;
  const size_t rowbase = (size_t)b*4096 + (blockIdx.x & 127)*32;
  const int lane = t & 63, w = t >> 6, l15 = lane & 15, lg = lane >> 4;
  if (t<32) tws[t] = fmaxf(twg[rowbase + t], 0.f);
  if (t<16) cs[t]=0.f;
  // qk fragments (waves 0,1 only), issued early so they're in flight under staging
  bf16x8 qkf[8];
  if (w<2) {
    const short* qrow = qk + ((size_t)(b*16+l15))*256 + lg*8;
    #pragma unroll
    for (int kk=0;kk<8;kk++) qkf[kk] = *(const bf16x8*)(qrow + kk*32);
  }
  if (LNIN) {
    if (t < 64)       *(float4*)&lnwb[t*4]           = ld4(lnw + t*4);
    else if (t < 128) *(float4*)&lnwb[256+(t-64)*4]  = ld4(lnb + (t-64)*4);
    __syncthreads();   // lnwb visible
    const float* ing = inputs + rowbase*256;
    const int r = t>>3, c = t&7;        // 8 lanes per row, 32 rows
    float4 vv[8];
    #pragma unroll
    for (int k=0;k<8;k++) vv[k] = ld4(ing + r*256 + (c+8*k)*4);
    float s=0.f, sq=0.f;
    #pragma unroll
    for (int k=0;k<8;k++){
      s  += vv[k].x+vv[k].y+vv[k].z+vv[k].w;
      sq += vv[k].x*vv[k].x+vv[k].y*vv[k].y+vv[k].z*vv[k].z+vv[k].w*vv[k].w;
    }
    s += __shfl_xor(s,1);  s += __shfl_xor(s,2);  s += __shfl_xor(s,4);
    sq += __shfl_xor(sq,1); sq += __shfl_xor(sq,2); sq += __shfl_xor(sq,4);
    float mean = s*(1.f/256.f);
    float rstd = rsqrtf(sq*(1.f/256.f) - mean*mean + LNEPS_);
    short* xw = xbf + rowbase*256;
    const int sw = XSW(r);
    #pragma unroll
    for (int k=0;k<8;k++){
      int d0 = (c+8*k)*4;
      float4 wv = *(float4*)&lnwb[d0];
      float4 bv = *(float4*)&lnwb[256+d0];
      s16x4 pk;
      pk[0]=f2bf((vv[k].x-mean)*rstd*wv.x+bv.x);
      pk[1]=f2bf((vv[k].y-mean)*rstd*wv.y+bv.y);
      pk[2]=f2bf((vv[k].z-mean)*rstd*wv.z+bv.z);
      pk[3]=f2bf((vv[k].w-mean)*rstd*wv.w+bv.w);
      *(s16x4*)&Xs[r*256 + (d0 ^ sw)] = pk;    // swizzled LDS
      *(s16x4*)&xw[r*256 + d0] = pk;           // linear global
    }
  } else {
    // stage 32 rows (16KB): 4 uint4 per thread, issue all loads then write LDS
    uint4 pf[4];
    const short* xg = xbf + rowbase*256;
    #pragma unroll
    for (int i=0;i<4;i++){
      int idx = t + i*256;
      pf[i] = *(const uint4*)&xg[(size_t)(idx>>5)*256 + (idx&31)*8];
    }
    #pragma unroll
    for (int i=0;i<4;i++){
      int idx = t + i*256, row = idx>>5;
      *(uint4*)&Xs[row*256 + (((idx&31)*8) ^ XSW(row))] = pf[i];
    }
  }
  __syncthreads();
  // GEMM1 + softmax on waves 0,1: D[row][s] = x_row . qk_s, rows w*16..w*16+15
  if (w<2) {
    f32x4 acc = {0.f,0.f,0.f,0.f};
    const int ra = w*16+l15, sa = XSW(ra);
    #pragma unroll
    for (int kk=0;kk<8;kk++){
      bf16x8 af = *(const bf16x8*)&Xs[ra*256 + ((kk*32+lg*8) ^ sa)];
      acc = __builtin_amdgcn_mfma_f32_16x16x32_bf16(af, qkf[kk], acc, 0,0,0);
    }
    float a4[4];
    #pragma unroll
    for (int q=0;q<4;q++){
      float v = acc[q]*0.0625f;          // * D^-0.5
      float m = v;
      #pragma unroll
      for (int d=1; d<16; d<<=1) m = fmaxf(m, __shfl_xor(m, d, 16));
      float e = __expf(v-m);
      float se = e;
      #pragma unroll
      for (int d=1; d<16; d<<=1) se += __shfl_xor(se, d, 16);
      int row = w*16 + lg*4 + q;
      float a = (e/se)*tws[row];
      a4[q] = a;
      if (WATTN)
        attn_un[(rowbase + row)*16 + l15] = a;
    }
    float psum = a4[0]+a4[1]+a4[2]+a4[3];
    psum += __shfl_xor(psum, 16);
    psum += __shfl_xor(psum, 32);
    if (lane<16) atomicAdd(&cs[l15], psum);
    s16x4 pk; pk[0]=f2bf(a4[0]); pk[1]=f2bf(a4[1]); pk[2]=f2bf(a4[2]); pk[3]=f2bf(a4[3]);
    *(s16x4*)&Pt[l15*40 + w*16 + lg*4] = pk;
  }
  __syncthreads();
  // GEMM2 (K=32): ux[s][e] = P^T @ X ; wave w owns e-cols [w*64, w*64+64)
  f32x4 uacc[4] = {};
  {
    bf16x8 a2 = *(const bf16x8*)&Pt[l15*40 + lg*8];
    #pragma unroll
    for (int tt=0;tt<4;tt++){
      int col = w*64 + tt*16 + l15;
      bf16x8 b2;
      #pragma unroll
      for (int j=0;j<8;j++){
        int r2 = lg*8 + j;
        b2[j] = Xs[r2*256 + (col ^ XSW(r2))];
      }
      uacc[tt] = __builtin_amdgcn_mfma_f32_16x16x32_bf16(a2, b2, uacc[tt], 0,0,0);
    }
  }
  if (t<16) colsum_part[blockIdx.x*16 + t] = cs[t];
  __syncthreads();   // all waves done reading Xs before overwrite
  // bounce uacc through Xs (reused as [16][256] bf16) for coalesced stores
  #pragma unroll
  for (int tt=0;tt<4;tt++)
    #pragma unroll
    for (int q=0;q<4;q++)
      Xs[(lg*4+q)*256 + w*64 + tt*16 + l15] = f2bf(uacc[tt][q]);
  __syncthreads();
  short* up = ux_part + (size_t)blockIdx.x*4096;
  #pragma unroll
  for (int i=0;i<2;i++){
    int idx = t + i*256;
    *(uint4*)&up[idx*8] = *(const uint4*)&Xs[idx*8];
  }
}

// ---------------- reduce ux partials over 128 chunks (+fold 1/(colsum+eps)) ----------------
__global__ __launch_bounds__(256) void k_reduce(const short* __restrict__ uxp,
    const float* __restrict__ csp, short* __restrict__ uxr, float* __restrict__ csr) {
  int r = blockIdx.x;          // b*16+s
  int b = r>>4, s = r&15;
  int t = threadIdx.x;
  float cs = 0.f;
  #pragma unroll 8
  for (int k=0;k<128;k++) cs += csp[((b<<7)+k)*16 + s];
  float u = 0.f;
  #pragma unroll 8
  for (int k=0;k<128;k++) u += bf2f(uxp[(size_t)((b<<7)+k)*4096 + s*256 + t]);
  uxr[(size_t)r*256+t] = f2bf(u/(cs+EPS_));
  if (t==0) csr[r] = cs;
}

// ---------------- gi|gh GEMM: gig[row][0:768]=uxr@M^T+bih, [768:1536]=slotsb@whh^T+bhh ----
__global__ __launch_bounds__(256) void k_gigh(
    const short* __restrict__ uxr, const short* __restrict__ slotsb,
    const short* __restrict__ Mb, const short* __restrict__ whhb,
    const float* __restrict__ bih, const float* __restrict__ bhh,
    float* __restrict__ gig) {
  __shared__ short As[64*40];
  __shared__ short Ws[64*40];
  const int t=threadIdx.x, bn=blockIdx.x, bm=blockIdx.y;
  const short* A; const short* W; const float* bias; int wo;
  if (bn<12) { A=uxr;    W=Mb   + (size_t)bn*64*256;      bias=bih; wo=bn*64; }
  else       { A=slotsb; W=whhb + (size_t)(bn-12)*64*256; bias=bhh; wo=(bn-12)*64; }
  const int w=t>>6, lane=t&63, l15=lane&15, lg=lane>>4;
  f32x4 acc[4]={};
  for (int k0=0;k0<256;k0+=32){
    __syncthreads();
    *(uint4*)&As[(t>>2)*40+(t&3)*8] = *(const uint4*)&A[(size_t)(bm*64+(t>>2))*256 + k0 + (t&3)*8];
    *(uint4*)&Ws[(t>>2)*40+(t&3)*8] = *(const uint4*)&W[(size_t)(t>>2)*256 + k0 + (t&3)*8];
    __syncthreads();
    bf16x8 af = *(const bf16x8*)&As[(w*16+l15)*40+lg*8];
    #pragma unroll
    for (int ct=0;ct<4;ct++){
      bf16x8 bfr = *(const bf16x8*)&Ws[(ct*16+l15)*40+lg*8];
      acc[ct]=__builtin_amdgcn_mfma_f32_16x16x32_bf16(af,bfr,acc[ct],0,0,0);
    }
  }
  #pragma unroll
  for (int ct=0;ct<4;ct++){
    float bv = bias[wo + ct*16 + l15];
    #pragma unroll
    for (int q=0;q<4;q++){
      int row = bm*64 + w*16 + lg*4 + q;
      gig[(size_t)row*1536 + bn*64 + ct*16 + l15] = acc[ct][q] + bv;
    }
  }
}

// ---------------- MLP1: hb = gelu(lnmb @ w1^T + b1), bf16 ----------------
__global__ __launch_bounds__(256) void k_mlp1(
    const short* __restrict__ lnmb, const short* __restrict__ w1b,
    const float* __restrict__ b1, short* __restrict__ hb) {
  __shared__ short As[64*40];
  __shared__ short Ws[64*40];
  const int t=threadIdx.x, bn=blockIdx.x, bm=blockIdx.y;
  const int w=t>>6, lane=t&63, l15=lane&15, lg=lane>>4;
  f32x4 acc[4]={};
  for (int k0=0;k0<256;k0+=32){
    __syncthreads();
    *(uint4*)&As[(t>>2)*40+(t&3)*8] = *(const uint4*)&lnmb[(size_t)(bm*64+(t>>2))*256 + k0 + (t&3)*8];
    *(uint4*)&Ws[(t>>2)*40+(t&3)*8] = *(const uint4*)&w1b[(size_t)(bn*64+(t>>2))*256 + k0 + (t&3)*8];
    __syncthreads();
    bf16x8 af = *(const bf16x8*)&As[(w*16+l15)*40+lg*8];
    #pragma unroll
    for (int ct=0;ct<4;ct++){
      bf16x8 bfr = *(const bf16x8*)&Ws[(ct*16+l15)*40+lg*8];
      acc[ct]=__builtin_amdgcn_mfma_f32_16x16x32_bf16(af,bfr,acc[ct],0,0,0);
    }
  }
  #pragma unroll
  for (int ct=0;ct<4;ct++){
    float bv = b1[bn*64 + ct*16 + l15];
    #pragma unroll
    for (int q=0;q<4;q++){
      int row = bm*64 + w*16 + lg*4 + q;
      float v = acc[ct][q] + bv;
      v = 0.5f*v*(1.f+erff(v*0.70710678118654752f));
      hb[(size_t)row*512 + bn*64 + ct*16 + l15] = f2bf(v);
    }
  }
}

// ---------------- GRU gates + LayerNorm(ln_m), wave per row ----------------
__global__ __launch_bounds__(256) void k_gates(const float* __restrict__ gig,
    const float* __restrict__ lw, const float* __restrict__ lb,
    float* __restrict__ slots, short* __restrict__ lnmb) {
  int row  = blockIdx.x*4 + (threadIdx.x>>6);
  int lane = threadIdx.x & 63;
  const float* gi = gig + (size_t)row*1536 + lane*4;
  float4 ir = ld4(gi), iz = ld4(gi+256), inn = ld4(gi+512);
  float4 hr = ld4(gi+768), hz = ld4(gi+1024), hn = ld4(gi+1280);
  float* sp = slots + (size_t)row*256 + lane*4;
  float4 h = ld4(sp);
  float hp[4];
  {
    float r0 = 1.f/(1.f+__expf(-(ir.x+hr.x))); float z0 = 1.f/(1.f+__expf(-(iz.x+hz.x)));
    hp[0] = (1.f-z0)*tanhf(inn.x + r0*hn.x) + z0*h.x;
    float r1 = 1.f/(1.f+__expf(-(ir.y+hr.y))); float z1 = 1.f/(1.f+__expf(-(iz.y+hz.y)));
    hp[1] = (1.f-z1)*tanhf(inn.y + r1*hn.y) + z1*h.y;
    float r2 = 1.f/(1.f+__expf(-(ir.z+hr.z))); float z2 = 1.f/(1.f+__expf(-(iz.z+hz.z)));
    hp[2] = (1.f-z2)*tanhf(inn.z + r2*hn.z) + z2*h.z;
    float r3 = 1.f/(1.f+__expf(-(ir.w+hr.w))); float z3 = 1.f/(1.f+__expf(-(iz.w+hz.w)));
    hp[3] = (1.f-z3)*tanhf(inn.w + r3*hn.w) + z3*h.w;
  }
  float s = hp[0]+hp[1]+hp[2]+hp[3];
  float sq = hp[0]*hp[0]+hp[1]*hp[1]+hp[2]*hp[2]+hp[3]*hp[3];
  #pragma unroll
  for (int d=1; d<64; d<<=1) { s += __shfl_xor(s,d); sq += __shfl_xor(sq,d); }
  float mean = s*(1.f/256.f);
  float rstd = rsqrtf(sq*(1.f/256.f) - mean*mean + LNEPS_);
  float4 wv = ld4(lw+lane*4), bv = ld4(lb+lane*4);
  *(float4*)sp = make_float4(hp[0],hp[1],hp[2],hp[3]);
  short4 o;
  o.x = f2bf((hp[0]-mean)*rstd*wv.x+bv.x);
  o.y = f2bf((hp[1]-mean)*rstd*wv.y+bv.y);
  o.z = f2bf((hp[2]-mean)*rstd*wv.z+bv.z);
  o.w = f2bf((hp[3]-mean)*rstd*wv.w+bv.w);
  *(short4*)(lnmb + (size_t)row*256 + lane*4) = o;
}

// ---------------- slot tail: [MLP2+res | slots-init] + LN_s + qk-GEMM ----------------
// MODE 0: v = hb@w2^T+b2+res(slots), write slots f32+slotsb, LN_s -> qk
// MODE 1: v = mu + sigma*noise (init), write slots f32+slotsb, LN_s -> qk
// MODE 2: v = hb@w2^T+b2+res(slots), write sout (=out_slots) only
template<int MODE>
__global__ __launch_bounds__(256) void k_slotend(
    const short* __restrict__ hb, const short* __restrict__ w2b, const float* __restrict__ b2,
    const float* __restrict__ mu, const float* __restrict__ ls, const float* __restrict__ noise,
    const float* __restrict__ res, float* __restrict__ sout, short* __restrict__ slotsb,
    const float* __restrict__ lnsw, const float* __restrict__ lnsb,
    const short* __restrict__ MTb, short* __restrict__ qk) {
  __shared__ short As[64*40];
  __shared__ short Ws[256*40];
  __shared__ short lnS[64*264];
  const int t=threadIdx.x, bm=blockIdx.x;
  const int w=t>>6, lane=t&63, l15=lane&15, lg=lane>>4;
  float v[16][4];
  if (MODE==1) {
    #pragma unroll
    for (int ct=0;ct<16;ct++){
      int col = ct*16+l15;
      float m = mu[col], sg = fmaxf(__expf(ls[col]),1e-6f);
      #pragma unroll
      for (int q=0;q<4;q++){
        int row = bm*64 + w*16 + lg*4 + q;
        v[ct][q] = m + sg*noise[(size_t)row*256+col];
      }
    }
  } else {
    f32x4 acc[16]={};
    for (int k0=0;k0<512;k0+=32){
      __syncthreads();
      *(uint4*)&As[(t>>2)*40+(t&3)*8] = *(const uint4*)&hb[(size_t)(bm*64+(t>>2))*512 + k0 + (t&3)*8];
      // stage 256 rows x 32 k of w2b: 1024 uint4 -> 4 iterations (NOT 8: R3 OOB lesson)
      #pragma unroll
      for (int i=0;i<4;i++){ int idx=t+i*256;
        *(uint4*)&Ws[(idx>>2)*40+(idx&3)*8] = *(const uint4*)&w2b[(size_t)(idx>>2)*512 + k0 + (idx&3)*8]; }
      __syncthreads();
      bf16x8 af = *(const bf16x8*)&As[(w*16+l15)*40+lg*8];
      #pragma unroll
      for (int ct=0;ct<16;ct++){
        bf16x8 bfr = *(const bf16x8*)&Ws[(ct*16+l15)*40+lg*8];
        acc[ct]=__builtin_amdgcn_mfma_f32_16x16x32_bf16(af,bfr,acc[ct],0,0,0);
      }
    }
    #pragma unroll
    for (int ct=0;ct<16;ct++){
      int col = ct*16+l15;
      float bv = b2[col];
      #pragma unroll
      for (int q=0;q<4;q++){
        int row = bm*64 + w*16 + lg*4 + q;
        v[ct][q] = acc[ct][q] + bv + res[(size_t)row*256+col];
      }
    }
  }
  float s[4]={0,0,0,0}, sq[4]={0,0,0,0};
  #pragma unroll
  for (int ct=0;ct<16;ct++)
    #pragma unroll
    for (int q=0;q<4;q++){ s[q]+=v[ct][q]; sq[q]+=v[ct][q]*v[ct][q]; }
  #pragma unroll
  for (int q=0;q<4;q++){
    #pragma unroll
    for (int d=1; d<16; d<<=1){ s[q]+=__shfl_xor(s[q],d,16); sq[q]+=__shfl_xor(sq[q],d,16); }
  }
  #pragma unroll
  for (int ct=0;ct<16;ct++){
    int col = ct*16+l15;
    float lw = (MODE!=2) ? lnsw[col] : 0.f;
    float lb = (MODE!=2) ? lnsb[col] : 0.f;
    #pragma unroll
    for (int q=0;q<4;q++){
      int row = bm*64 + w*16 + lg*4 + q;
      sout[(size_t)row*256+col] = v[ct][q];
      if (MODE!=2){
        float mean = s[q]*(1.f/256.f);
        float rstd = rsqrtf(sq[q]*(1.f/256.f)-mean*mean+LNEPS_);
        slotsb[(size_t)row*256+col] = f2bf(v[ct][q]);
        lnS[(w*16+lg*4+q)*264 + col] = f2bf((v[ct][q]-mean)*rstd*lw+lb);
      }
    }
  }
  if (MODE!=2){
    f32x4 qa[16]={};
    for (int k0=0;k0<256;k0+=32){
      __syncthreads();
      #pragma unroll
      for (int i=0;i<4;i++){ int idx=t+i*256;   // 256 rows x 32 k = 1024 uint4
        *(uint4*)&Ws[(idx>>2)*40+(idx&3)*8] = *(const uint4*)&MTb[(size_t)(idx>>2)*256 + k0 + (idx&3)*8]; }
      __syncthreads();
      bf16x8 af = *(const bf16x8*)&lnS[(w*16+l15)*264 + k0 + lg*8];
      #pragma unroll
      for (int ct=0;ct<16;ct++){
        bf16x8 bfr = *(const bf16x8*)&Ws[(ct*16+l15)*40+lg*8];
        qa[ct]=__builtin_amdgcn_mfma_f32_16x16x32_bf16(af,bfr,qa[ct],0,0,0);
      }
    }
    #pragma unroll
    for (int ct=0;ct<16;ct++)
      #pragma unroll
      for (int q=0;q<4;q++)
        qk[(size_t)(bm*64+w*16+lg*4+q)*256 + ct*16+l15] = f2bf(qa[ct][q]);
  }
}

// ---------------- final attn normalization (in place on d_out) ----------------
__global__ __launch_bounds__(256) void k_attn_norm(float* __restrict__ au,
    const float* __restrict__ cs) {
  size_t i = ((size_t)blockIdx.x*256 + threadIdx.x)*4;
  float4 v = ld4(au + i);
  int s = (int)(i & 15);
  size_t b = i >> 16;           // 4096*16 elems per batch
  const float* c = cs + b*16 + s;
  float4 o;
  o.x = v.x/(c[0]+EPS_); o.y = v.y/(c[1]+EPS_);
  o.z = v.z/(c[2]+EPS_); o.w = v.w/(c[3]+EPS_);
  *(float4*)(au + i) = o;
}

extern "C" void kernel_launch(void* const* d_in, const int* in_sizes, int n_in,
                              void* d_out, int out_size, void* d_ws, size_t ws_size,
                              hipStream_t stream) {
  const float* inputs   = (const float*)d_in[0];
  const float* token_w  = (const float*)d_in[1];
  const float* noise    = (const float*)d_in[2];
  const float* ln_in_w  = (const float*)d_in[3];
  const float* ln_in_b  = (const float*)d_in[4];
  const float* ln_s_w   = (const float*)d_in[5];
  const float* ln_s_b   = (const float*)d_in[6];
  const float* ln_m_w   = (const float*)d_in[7];
  const float* ln_m_b   = (const float*)d_in[8];
  const float* Wk       = (const float*)d_in[9];
  const float* Wv       = (const float*)d_in[10];
  const float* Wq       = (const float*)d_in[11];
  const float* gru_wih  = (const float*)d_in[12];
  const float* gru_whh  = (const float*)d_in[13];
  const float* gru_bih  = (const float*)d_in[14];
  const float* gru_bhh  = (const float*)d_in[15];
  const float* mlp_w1   = (const float*)d_in[16];
  const float* mlp_b1   = (const float*)d_in[17];
  const float* mlp_w2   = (const float*)d_in[18];
  const float* mlp_b2   = (const float*)d_in[19];
  const float* slots_mu = (const float*)d_in[20];
  const float* slots_ls = (const float*)d_in[21];

  float* out_slots = (float*)d_out;            // [32,16,256]
  float* out_attn  = out_slots + 131072;       // [32,4096,16]

  char* wsb = (char*)d_ws;
  size_t off = 0;
  short* xbf     = (short*)(wsb + off); off += 67108864;   // x bf16 [B,N,D]
  short* ux_part = (short*)(wsb + off); off += 33554432;   // [4096][16][256] bf16
  float* cs_part = (float*)(wsb + off); off += 262144;     // [4096][16]
  float* cs_red  = (float*)(wsb + off); off += 2048;       // [B*S]
  short* qk      = (short*)(wsb + off); off += 262144;     // [B*S][D] bf16
  short* uxr     = (short*)(wsb + off); off += 262144;     // reduced ux bf16
  short* MTb     = (short*)(wsb + off); off += 131072;     // Wq^T Wk bf16
  short* Mb      = (short*)(wsb + off); off += 393216;     // wih@Wv bf16 [768][256]
  float* gig     = (float*)(wsb + off); off += 3145728;    // [512][1536] f32
  float* slots   = (float*)(wsb + off); off += 524288;     // slots f32
  short* slotsb  = (short*)(wsb + off); off += 262144;     // slots bf16
  short* lnmb    = (short*)(wsb + off); off += 262144;     // LN_m bf16
  short* hb      = (short*)(wsb + off); off += 524288;     // mlp hidden bf16 [512][512]
  short* whhb    = (short*)(wsb + off); off += 393216;
  short* w1b     = (short*)(wsb + off); off += 262144;
  short* w2b     = (short*)(wsb + off); off += 262144;

  k_prep<<<704,256,0,stream>>>(Wq, Wk, gru_wih, Wv, gru_whh, mlp_w1, mlp_w2,
                               MTb, Mb, whhb, w1b, w2b);
  k_slotend<1><<<8,256,0,stream>>>(nullptr, nullptr, nullptr, slots_mu, slots_ls, noise,
                                   nullptr, slots, slotsb, ln_s_w, ln_s_b, MTb, qk);
  for (int it=0; it<3; ++it) {
    if (it==0)
      k3<1,0><<<4096,256,0,stream>>>(inputs, ln_in_w, ln_in_b, xbf, qk, token_w,
                                     ux_part, cs_part, out_attn);
    else if (it==1)
      k3<0,0><<<4096,256,0,stream>>>(inputs, ln_in_w, ln_in_b, xbf, qk, token_w,
                                     ux_part, cs_part, out_attn);
    else
      k3<0,1><<<4096,256,0,stream>>>(inputs, ln_in_w, ln_in_b, xbf, qk, token_w,
                                     ux_part, cs_part, out_attn);
    k_reduce<<<512,256,0,stream>>>(ux_part, cs_part, uxr, cs_red);
    k_gigh<<<dim3(24,8),256,0,stream>>>(uxr, slotsb, Mb, whhb, gru_bih, gru_bhh, gig);
    k_gates<<<128,256,0,stream>>>(gig, ln_m_w, ln_m_b, slots, lnmb);
    k_mlp1<<<dim3(8,8),256,0,stream>>>(lnmb, w1b, mlp_b1, hb);
    if (it<2)
      k_slotend<0><<<8,256,0,stream>>>(hb, w2b, mlp_b2, nullptr, nullptr, nullptr,
                                       slots, slots, slotsb, ln_s_w, ln_s_b, MTb, qk);
    else
      k_slotend<2><<<8,256,0,stream>>>(hb, w2b, mlp_b2, nullptr, nullptr, nullptr,
                                       slots, out_slots, slotsb, ln_s_w, ln_s_b, MTb, qk);
  }
  k_attn_norm<<<2048,256,0,stream>>>(out_attn, cs_red);
}

// Round 9
// 271.924 us; speedup vs baseline: 1.2144x; 1.2144x over previous
//
#include <hip/hip_runtime.h>
#include <hip/hip_bf16.h>
#include <math.h>

// SlotAttention on MI355X.
// Factorizations:
//   k,v never materialized:  qk = LN(slots) @ (Wq^T Wk);  logits = x·qk
//   updates feeds only the GRU input GEMM:  gi = uxr @ (wih·Wv)^T  (M precomputed)
//   token-normalization 1/(colsum+eps) commutes out of the P^T@X accumulation.
// R9: R8 structure (32-row blocks, grid 4096, bf16 partials) but WITHOUT the
//     forced launch_bounds(256,6): that capped VGPR at ~40 and spilled ~300B/
//     thread to scratch (WRITE_SIZE 351MB vs 35MB expected). Natural VGPR ->
//     no spills; LDS 20KB permits 8 blocks/CU; VGPR sets the occupancy cap.

#define EPS_ 1e-8f
#define LNEPS_ 1e-5f
// Xs element-index swizzle (R6, verified): spreads GEMM2's row-gather onto
// disjoint bank octets. Granularity 8 shorts -> b128 reads intact.
#define XSW(r) ((((r)&7)<<3) ^ ((((r)>>3)&3)<<4))

typedef __attribute__((ext_vector_type(8))) short bf16x8;
typedef __attribute__((ext_vector_type(4))) float f32x4;
typedef __attribute__((ext_vector_type(4))) short s16x4;

static __device__ __forceinline__ short f2bf(float f) {
  __hip_bfloat16 h = __float2bfloat16(f);
  union { __hip_bfloat16 h; short s; } u; u.h = h; return u.s;
}
static __device__ __forceinline__ float bf2f(short s) {
  union { float f; unsigned u; } x; x.u = ((unsigned)(unsigned short)s) << 16; return x.f;
}
static __device__ __forceinline__ float4 ld4(const float* p){ return *(const float4*)p; }

// ---------------- prep: MT = Wq^T Wk, M = wih@Wv, bf16 casts ----------------
__global__ __launch_bounds__(256) void k_prep(
    const float* __restrict__ Wq, const float* __restrict__ Wk,
    const float* __restrict__ wih, const float* __restrict__ Wv,
    const float* __restrict__ whh, const float* __restrict__ w1, const float* __restrict__ w2,
    short* __restrict__ MTb, short* __restrict__ Mb, short* __restrict__ whhb,
    short* __restrict__ w1b, short* __restrict__ w2b) {
  int blk = blockIdx.x, t = threadIdx.x;
  if (blk < 64) {                 // MT[e][f] = sum_d Wq[d][f]*Wk[d][e]
    int e0 = blk*4;
    float a0=0,a1=0,a2=0,a3=0;
    for (int d=0; d<256; d++) {
      float qv = Wq[d*256 + t];
      a0 += qv*Wk[d*256+e0];   a1 += qv*Wk[d*256+e0+1];
      a2 += qv*Wk[d*256+e0+2]; a3 += qv*Wk[d*256+e0+3];
    }
    MTb[(e0  )*256+t]=f2bf(a0); MTb[(e0+1)*256+t]=f2bf(a1);
    MTb[(e0+2)*256+t]=f2bf(a2); MTb[(e0+3)*256+t]=f2bf(a3);
  } else if (blk < 256) {         // M[n][e] = sum_d wih[n][d]*Wv[d][e]
    int n0 = (blk-64)*4;
    float a0=0,a1=0,a2=0,a3=0;
    for (int d=0; d<256; d++) {
      float vv = Wv[d*256 + t];
      a0 += wih[(n0  )*256+d]*vv; a1 += wih[(n0+1)*256+d]*vv;
      a2 += wih[(n0+2)*256+d]*vv; a3 += wih[(n0+3)*256+d]*vv;
    }
    Mb[(size_t)(n0  )*256+t]=f2bf(a0); Mb[(size_t)(n0+1)*256+t]=f2bf(a1);
    Mb[(size_t)(n0+2)*256+t]=f2bf(a2); Mb[(size_t)(n0+3)*256+t]=f2bf(a3);
  } else {                        // casts: whh 49152, w1 32768, w2 32768 float4s
    int c = (blk-256)*256 + t;
    const float* src; short* dst;
    if (c < 49152) { src=whh; dst=whhb; }
    else if ((c-=49152) < 32768) { src=w1; dst=w1b; }
    else { c-=32768; src=w2; dst=w2b; }
    float4 v = ld4(src + (size_t)c*4);
    short4 o; o.x=f2bf(v.x); o.y=f2bf(v.y); o.z=f2bf(v.z); o.w=f2bf(v.w);
    *(short4*)(dst + (size_t)c*4) = o;
  }
}

// ---------------- fused attention pass (+optional LN-of-inputs) ----------------
// grid = B*128 = 4096 blocks (ONE 32-token-row tile each), 256 threads = 4 waves.
// GEMM1+softmax on waves 0,1 (2 row-tiles); GEMM2 (K=32) on all 4 waves.
template<int LNIN, int WATTN>
__global__ __launch_bounds__(256) void k3(
    const float* __restrict__ inputs, const float* __restrict__ lnw, const float* __restrict__ lnb,
    short* __restrict__ xbf, const short* __restrict__ qk, const float* __restrict__ twg,
    short* __restrict__ ux_part, float* __restrict__ colsum_part, float* __restrict__ attn_un) {
  __shared__ __align__(16) short Xs[32*256];   // 16KB: [row][elem ^ XSW(row)]
  __shared__ __align__(16) short Pt[16*40];    // P^T [s][32 rows], stride 40
  __shared__ float tws[32];
  __shared__ float cs[16];
  __shared__ float lnwb[512];
  const int t = threadIdx.x;
  const int b = blockIdx.x >> 7;
  const size_t rowbase = (size_t)b*4096 + (blockIdx.x & 127)*32;
  const int lane = t & 63, w = t >> 6, l15 = lane & 15, lg = lane >> 4;
  if (t<32) tws[t] = fmaxf(twg[rowbase + t], 0.f);
  if (t<16) cs[t]=0.f;
  if (LNIN) {
    if (t < 64)       *(float4*)&lnwb[t*4]           = ld4(lnw + t*4);
    else if (t < 128) *(float4*)&lnwb[256+(t-64)*4]  = ld4(lnb + (t-64)*4);
    __syncthreads();   // lnwb visible
    const float* ing = inputs + rowbase*256;
    const int r = t>>3, c = t&7;        // 8 lanes per row, 32 rows
    float4 vv[8];
    #pragma unroll
    for (int k=0;k<8;k++) vv[k] = ld4(ing + r*256 + (c+8*k)*4);
    float s=0.f, sq=0.f;
    #pragma unroll
    for (int k=0;k<8;k++){
      s  += vv[k].x+vv[k].y+vv[k].z+vv[k].w;
      sq += vv[k].x*vv[k].x+vv[k].y*vv[k].y+vv[k].z*vv[k].z+vv[k].w*vv[k].w;
    }
    s += __shfl_xor(s,1);  s += __shfl_xor(s,2);  s += __shfl_xor(s,4);
    sq += __shfl_xor(sq,1); sq += __shfl_xor(sq,2); sq += __shfl_xor(sq,4);
    float mean = s*(1.f/256.f);
    float rstd = rsqrtf(sq*(1.f/256.f) - mean*mean + LNEPS_);
    short* xw = xbf + rowbase*256;
    const int sw = XSW(r);
    #pragma unroll
    for (int k=0;k<8;k++){
      int d0 = (c+8*k)*4;
      float4 wv = *(float4*)&lnwb[d0];
      float4 bv = *(float4*)&lnwb[256+d0];
      s16x4 pk;
      pk[0]=f2bf((vv[k].x-mean)*rstd*wv.x+bv.x);
      pk[1]=f2bf((vv[k].y-mean)*rstd*wv.y+bv.y);
      pk[2]=f2bf((vv[k].z-mean)*rstd*wv.z+bv.z);
      pk[3]=f2bf((vv[k].w-mean)*rstd*wv.w+bv.w);
      *(s16x4*)&Xs[r*256 + (d0 ^ sw)] = pk;    // swizzled LDS
      *(s16x4*)&xw[r*256 + d0] = pk;           // linear global
    }
  } else {
    // stage 32 rows (16KB): 4 uint4 per thread, issue all loads then write LDS
    uint4 pf[4];
    const short* xg = xbf + rowbase*256;
    #pragma unroll
    for (int i=0;i<4;i++){
      int idx = t + i*256;
      pf[i] = *(const uint4*)&xg[(size_t)(idx>>5)*256 + (idx&31)*8];
    }
    #pragma unroll
    for (int i=0;i<4;i++){
      int idx = t + i*256, row = idx>>5;
      *(uint4*)&Xs[row*256 + (((idx&31)*8) ^ XSW(row))] = pf[i];
    }
  }
  // qk fragments (waves 0,1 only) — loaded after staging to cut peak VGPR
  bf16x8 qkf[8];
  if (w<2) {
    const short* qrow = qk + ((size_t)(b*16+l15))*256 + lg*8;
    #pragma unroll
    for (int kk=0;kk<8;kk++) qkf[kk] = *(const bf16x8*)(qrow + kk*32);
  }
  __syncthreads();
  // GEMM1 + softmax on waves 0,1: D[row][s] = x_row . qk_s, rows w*16..w*16+15
  if (w<2) {
    f32x4 acc = {0.f,0.f,0.f,0.f};
    const int ra = w*16+l15, sa = XSW(ra);
    #pragma unroll
    for (int kk=0;kk<8;kk++){
      bf16x8 af = *(const bf16x8*)&Xs[ra*256 + ((kk*32+lg*8) ^ sa)];
      acc = __builtin_amdgcn_mfma_f32_16x16x32_bf16(af, qkf[kk], acc, 0,0,0);
    }
    float a4[4];
    #pragma unroll
    for (int q=0;q<4;q++){
      float v = acc[q]*0.0625f;          // * D^-0.5
      float m = v;
      #pragma unroll
      for (int d=1; d<16; d<<=1) m = fmaxf(m, __shfl_xor(m, d, 16));
      float e = __expf(v-m);
      float se = e;
      #pragma unroll
      for (int d=1; d<16; d<<=1) se += __shfl_xor(se, d, 16);
      int row = w*16 + lg*4 + q;
      float a = (e/se)*tws[row];
      a4[q] = a;
      if (WATTN)
        attn_un[(rowbase + row)*16 + l15] = a;
    }
    float psum = a4[0]+a4[1]+a4[2]+a4[3];
    psum += __shfl_xor(psum, 16);
    psum += __shfl_xor(psum, 32);
    if (lane<16) atomicAdd(&cs[l15], psum);
    s16x4 pk; pk[0]=f2bf(a4[0]); pk[1]=f2bf(a4[1]); pk[2]=f2bf(a4[2]); pk[3]=f2bf(a4[3]);
    *(s16x4*)&Pt[l15*40 + w*16 + lg*4] = pk;
  }
  __syncthreads();
  // GEMM2 (K=32): ux[s][e] = P^T @ X ; wave w owns e-cols [w*64, w*64+64)
  f32x4 uacc[4] = {};
  {
    bf16x8 a2 = *(const bf16x8*)&Pt[l15*40 + lg*8];
    #pragma unroll
    for (int tt=0;tt<4;tt++){
      int col = w*64 + tt*16 + l15;
      bf16x8 b2;
      #pragma unroll
      for (int j=0;j<8;j++){
        int r2 = lg*8 + j;
        b2[j] = Xs[r2*256 + (col ^ XSW(r2))];
      }
      uacc[tt] = __builtin_amdgcn_mfma_f32_16x16x32_bf16(a2, b2, uacc[tt], 0,0,0);
    }
  }
  if (t<16) colsum_part[blockIdx.x*16 + t] = cs[t];
  __syncthreads();   // all waves done reading Xs before overwrite
  // bounce uacc through Xs (reused as [16][256] bf16) for coalesced stores
  #pragma unroll
  for (int tt=0;tt<4;tt++)
    #pragma unroll
    for (int q=0;q<4;q++)
      Xs[(lg*4+q)*256 + w*64 + tt*16 + l15] = f2bf(uacc[tt][q]);
  __syncthreads();
  short* up = ux_part + (size_t)blockIdx.x*4096;
  #pragma unroll
  for (int i=0;i<2;i++){
    int idx = t + i*256;
    *(uint4*)&up[idx*8] = *(const uint4*)&Xs[idx*8];
  }
}

// ---------------- reduce ux partials over 128 chunks (+fold 1/(colsum+eps)) ----------------
__global__ __launch_bounds__(256) void k_reduce(const short* __restrict__ uxp,
    const float* __restrict__ csp, short* __restrict__ uxr, float* __restrict__ csr) {
  int r = blockIdx.x;          // b*16+s
  int b = r>>4, s = r&15;
  int t = threadIdx.x;
  float cs = 0.f;
  #pragma unroll 8
  for (int k=0;k<128;k++) cs += csp[((b<<7)+k)*16 + s];
  float u = 0.f;
  #pragma unroll 8
  for (int k=0;k<128;k++) u += bf2f(uxp[(size_t)((b<<7)+k)*4096 + s*256 + t]);
  uxr[(size_t)r*256+t] = f2bf(u/(cs+EPS_));
  if (t==0) csr[r] = cs;
}

// ---------------- gi|gh GEMM: gig[row][0:768]=uxr@M^T+bih, [768:1536]=slotsb@whh^T+bhh ----
__global__ __launch_bounds__(256) void k_gigh(
    const short* __restrict__ uxr, const short* __restrict__ slotsb,
    const short* __restrict__ Mb, const short* __restrict__ whhb,
    const float* __restrict__ bih, const float* __restrict__ bhh,
    float* __restrict__ gig) {
  __shared__ short As[64*40];
  __shared__ short Ws[64*40];
  const int t=threadIdx.x, bn=blockIdx.x, bm=blockIdx.y;
  const short* A; const short* W; const float* bias; int wo;
  if (bn<12) { A=uxr;    W=Mb   + (size_t)bn*64*256;      bias=bih; wo=bn*64; }
  else       { A=slotsb; W=whhb + (size_t)(bn-12)*64*256; bias=bhh; wo=(bn-12)*64; }
  const int w=t>>6, lane=t&63, l15=lane&15, lg=lane>>4;
  f32x4 acc[4]={};
  for (int k0=0;k0<256;k0+=32){
    __syncthreads();
    *(uint4*)&As[(t>>2)*40+(t&3)*8] = *(const uint4*)&A[(size_t)(bm*64+(t>>2))*256 + k0 + (t&3)*8];
    *(uint4*)&Ws[(t>>2)*40+(t&3)*8] = *(const uint4*)&W[(size_t)(t>>2)*256 + k0 + (t&3)*8];
    __syncthreads();
    bf16x8 af = *(const bf16x8*)&As[(w*16+l15)*40+lg*8];
    #pragma unroll
    for (int ct=0;ct<4;ct++){
      bf16x8 bfr = *(const bf16x8*)&Ws[(ct*16+l15)*40+lg*8];
      acc[ct]=__builtin_amdgcn_mfma_f32_16x16x32_bf16(af,bfr,acc[ct],0,0,0);
    }
  }
  #pragma unroll
  for (int ct=0;ct<4;ct++){
    float bv = bias[wo + ct*16 + l15];
    #pragma unroll
    for (int q=0;q<4;q++){
      int row = bm*64 + w*16 + lg*4 + q;
      gig[(size_t)row*1536 + bn*64 + ct*16 + l15] = acc[ct][q] + bv;
    }
  }
}

// ---------------- MLP1: hb = gelu(lnmb @ w1^T + b1), bf16 ----------------
__global__ __launch_bounds__(256) void k_mlp1(
    const short* __restrict__ lnmb, const short* __restrict__ w1b,
    const float* __restrict__ b1, short* __restrict__ hb) {
  __shared__ short As[64*40];
  __shared__ short Ws[64*40];
  const int t=threadIdx.x, bn=blockIdx.x, bm=blockIdx.y;
  const int w=t>>6, lane=t&63, l15=lane&15, lg=lane>>4;
  f32x4 acc[4]={};
  for (int k0=0;k0<256;k0+=32){
    __syncthreads();
    *(uint4*)&As[(t>>2)*40+(t&3)*8] = *(const uint4*)&lnmb[(size_t)(bm*64+(t>>2))*256 + k0 + (t&3)*8];
    *(uint4*)&Ws[(t>>2)*40+(t&3)*8] = *(const uint4*)&w1b[(size_t)(bn*64+(t>>2))*256 + k0 + (t&3)*8];
    __syncthreads();
    bf16x8 af = *(const bf16x8*)&As[(w*16+l15)*40+lg*8];
    #pragma unroll
    for (int ct=0;ct<4;ct++){
      bf16x8 bfr = *(const bf16x8*)&Ws[(ct*16+l15)*40+lg*8];
      acc[ct]=__builtin_amdgcn_mfma_f32_16x16x32_bf16(af,bfr,acc[ct],0,0,0);
    }
  }
  #pragma unroll
  for (int ct=0;ct<4;ct++){
    float bv = b1[bn*64 + ct*16 + l15];
    #pragma unroll
    for (int q=0;q<4;q++){
      int row = bm*64 + w*16 + lg*4 + q;
      float v = acc[ct][q] + bv;
      v = 0.5f*v*(1.f+erff(v*0.70710678118654752f));
      hb[(size_t)row*512 + bn*64 + ct*16 + l15] = f2bf(v);
    }
  }
}

// ---------------- GRU gates + LayerNorm(ln_m), wave per row ----------------
__global__ __launch_bounds__(256) void k_gates(const float* __restrict__ gig,
    const float* __restrict__ lw, const float* __restrict__ lb,
    float* __restrict__ slots, short* __restrict__ lnmb) {
  int row  = blockIdx.x*4 + (threadIdx.x>>6);
  int lane = threadIdx.x & 63;
  const float* gi = gig + (size_t)row*1536 + lane*4;
  float4 ir = ld4(gi), iz = ld4(gi+256), inn = ld4(gi+512);
  float4 hr = ld4(gi+768), hz = ld4(gi+1024), hn = ld4(gi+1280);
  float* sp = slots + (size_t)row*256 + lane*4;
  float4 h = ld4(sp);
  float hp[4];
  {
    float r0 = 1.f/(1.f+__expf(-(ir.x+hr.x))); float z0 = 1.f/(1.f+__expf(-(iz.x+hz.x)));
    hp[0] = (1.f-z0)*tanhf(inn.x + r0*hn.x) + z0*h.x;
    float r1 = 1.f/(1.f+__expf(-(ir.y+hr.y))); float z1 = 1.f/(1.f+__expf(-(iz.y+hz.y)));
    hp[1] = (1.f-z1)*tanhf(inn.y + r1*hn.y) + z1*h.y;
    float r2 = 1.f/(1.f+__expf(-(ir.z+hr.z))); float z2 = 1.f/(1.f+__expf(-(iz.z+hz.z)));
    hp[2] = (1.f-z2)*tanhf(inn.z + r2*hn.z) + z2*h.z;
    float r3 = 1.f/(1.f+__expf(-(ir.w+hr.w))); float z3 = 1.f/(1.f+__expf(-(iz.w+hz.w)));
    hp[3] = (1.f-z3)*tanhf(inn.w + r3*hn.w) + z3*h.w;
  }
  float s = hp[0]+hp[1]+hp[2]+hp[3];
  float sq = hp[0]*hp[0]+hp[1]*hp[1]+hp[2]*hp[2]+hp[3]*hp[3];
  #pragma unroll
  for (int d=1; d<64; d<<=1) { s += __shfl_xor(s,d); sq += __shfl_xor(sq,d); }
  float mean = s*(1.f/256.f);
  float rstd = rsqrtf(sq*(1.f/256.f) - mean*mean + LNEPS_);
  float4 wv = ld4(lw+lane*4), bv = ld4(lb+lane*4);
  *(float4*)sp = make_float4(hp[0],hp[1],hp[2],hp[3]);
  short4 o;
  o.x = f2bf((hp[0]-mean)*rstd*wv.x+bv.x);
  o.y = f2bf((hp[1]-mean)*rstd*wv.y+bv.y);
  o.z = f2bf((hp[2]-mean)*rstd*wv.z+bv.z);
  o.w = f2bf((hp[3]-mean)*rstd*wv.w+bv.w);
  *(short4*)(lnmb + (size_t)row*256 + lane*4) = o;
}

// ---------------- slot tail: [MLP2+res | slots-init] + LN_s + qk-GEMM ----------------
// MODE 0: v = hb@w2^T+b2+res(slots), write slots f32+slotsb, LN_s -> qk
// MODE 1: v = mu + sigma*noise (init), write slots f32+slotsb, LN_s -> qk
// MODE 2: v = hb@w2^T+b2+res(slots), write sout (=out_slots) only
template<int MODE>
__global__ __launch_bounds__(256) void k_slotend(
    const short* __restrict__ hb, const short* __restrict__ w2b, const float* __restrict__ b2,
    const float* __restrict__ mu, const float* __restrict__ ls, const float* __restrict__ noise,
    const float* __restrict__ res, float* __restrict__ sout, short* __restrict__ slotsb,
    const float* __restrict__ lnsw, const float* __restrict__ lnsb,
    const short* __restrict__ MTb, short* __restrict__ qk) {
  __shared__ short As[64*40];
  __shared__ short Ws[256*40];
  __shared__ short lnS[64*264];
  const int t=threadIdx.x, bm=blockIdx.x;
  const int w=t>>6, lane=t&63, l15=lane&15, lg=lane>>4;
  float v[16][4];
  if (MODE==1) {
    #pragma unroll
    for (int ct=0;ct<16;ct++){
      int col = ct*16+l15;
      float m = mu[col], sg = fmaxf(__expf(ls[col]),1e-6f);
      #pragma unroll
      for (int q=0;q<4;q++){
        int row = bm*64 + w*16 + lg*4 + q;
        v[ct][q] = m + sg*noise[(size_t)row*256+col];
      }
    }
  } else {
    f32x4 acc[16]={};
    for (int k0=0;k0<512;k0+=32){
      __syncthreads();
      *(uint4*)&As[(t>>2)*40+(t&3)*8] = *(const uint4*)&hb[(size_t)(bm*64+(t>>2))*512 + k0 + (t&3)*8];
      // stage 256 rows x 32 k of w2b: 1024 uint4 -> 4 iterations (NOT 8: R3 OOB lesson)
      #pragma unroll
      for (int i=0;i<4;i++){ int idx=t+i*256;
        *(uint4*)&Ws[(idx>>2)*40+(idx&3)*8] = *(const uint4*)&w2b[(size_t)(idx>>2)*512 + k0 + (idx&3)*8]; }
      __syncthreads();
      bf16x8 af = *(const bf16x8*)&As[(w*16+l15)*40+lg*8];
      #pragma unroll
      for (int ct=0;ct<16;ct++){
        bf16x8 bfr = *(const bf16x8*)&Ws[(ct*16+l15)*40+lg*8];
        acc[ct]=__builtin_amdgcn_mfma_f32_16x16x32_bf16(af,bfr,acc[ct],0,0,0);
      }
    }
    #pragma unroll
    for (int ct=0;ct<16;ct++){
      int col = ct*16+l15;
      float bv = b2[col];
      #pragma unroll
      for (int q=0;q<4;q++){
        int row = bm*64 + w*16 + lg*4 + q;
        v[ct][q] = acc[ct][q] + bv + res[(size_t)row*256+col];
      }
    }
  }
  float s[4]={0,0,0,0}, sq[4]={0,0,0,0};
  #pragma unroll
  for (int ct=0;ct<16;ct++)
    #pragma unroll
    for (int q=0;q<4;q++){ s[q]+=v[ct][q]; sq[q]+=v[ct][q]*v[ct][q]; }
  #pragma unroll
  for (int q=0;q<4;q++){
    #pragma unroll
    for (int d=1; d<16; d<<=1){ s[q]+=__shfl_xor(s[q],d,16); sq[q]+=__shfl_xor(sq[q],d,16); }
  }
  #pragma unroll
  for (int ct=0;ct<16;ct++){
    int col = ct*16+l15;
    float lw = (MODE!=2) ? lnsw[col] : 0.f;
    float lb = (MODE!=2) ? lnsb[col] : 0.f;
    #pragma unroll
    for (int q=0;q<4;q++){
      int row = bm*64 + w*16 + lg*4 + q;
      sout[(size_t)row*256+col] = v[ct][q];
      if (MODE!=2){
        float mean = s[q]*(1.f/256.f);
        float rstd = rsqrtf(sq[q]*(1.f/256.f)-mean*mean+LNEPS_);
        slotsb[(size_t)row*256+col] = f2bf(v[ct][q]);
        lnS[(w*16+lg*4+q)*264 + col] = f2bf((v[ct][q]-mean)*rstd*lw+lb);
      }
    }
  }
  if (MODE!=2){
    f32x4 qa[16]={};
    for (int k0=0;k0<256;k0+=32){
      __syncthreads();
      #pragma unroll
      for (int i=0;i<4;i++){ int idx=t+i*256;   // 256 rows x 32 k = 1024 uint4
        *(uint4*)&Ws[(idx>>2)*40+(idx&3)*8] = *(const uint4*)&MTb[(size_t)(idx>>2)*256 + k0 + (idx&3)*8]; }
      __syncthreads();
      bf16x8 af = *(const bf16x8*)&lnS[(w*16+l15)*264 + k0 + lg*8];
      #pragma unroll
      for (int ct=0;ct<16;ct++){
        bf16x8 bfr = *(const bf16x8*)&Ws[(ct*16+l15)*40+lg*8];
        qa[ct]=__builtin_amdgcn_mfma_f32_16x16x32_bf16(af,bfr,qa[ct],0,0,0);
      }
    }
    #pragma unroll
    for (int ct=0;ct<16;ct++)
      #pragma unroll
      for (int q=0;q<4;q++)
        qk[(size_t)(bm*64+w*16+lg*4+q)*256 + ct*16+l15] = f2bf(qa[ct][q]);
  }
}

// ---------------- final attn normalization (in place on d_out) ----------------
__global__ __launch_bounds__(256) void k_attn_norm(float* __restrict__ au,
    const float* __restrict__ cs) {
  size_t i = ((size_t)blockIdx.x*256 + threadIdx.x)*4;
  float4 v = ld4(au + i);
  int s = (int)(i & 15);
  size_t b = i >> 16;           // 4096*16 elems per batch
  const float* c = cs + b*16 + s;
  float4 o;
  o.x = v.x/(c[0]+EPS_); o.y = v.y/(c[1]+EPS_);
  o.z = v.z/(c[2]+EPS_); o.w = v.w/(c[3]+EPS_);
  *(float4*)(au + i) = o;
}

extern "C" void kernel_launch(void* const* d_in, const int* in_sizes, int n_in,
                              void* d_out, int out_size, void* d_ws, size_t ws_size,
                              hipStream_t stream) {
  const float* inputs   = (const float*)d_in[0];
  const float* token_w  = (const float*)d_in[1];
  const float* noise    = (const float*)d_in[2];
  const float* ln_in_w  = (const float*)d_in[3];
  const float* ln_in_b  = (const float*)d_in[4];
  const float* ln_s_w   = (const float*)d_in[5];
  const float* ln_s_b   = (const float*)d_in[6];
  const float* ln_m_w   = (const float*)d_in[7];
  const float* ln_m_b   = (const float*)d_in[8];
  const float* Wk       = (const float*)d_in[9];
  const float* Wv       = (const float*)d_in[10];
  const float* Wq       = (const float*)d_in[11];
  const float* gru_wih  = (const float*)d_in[12];
  const float* gru_whh  = (const float*)d_in[13];
  const float* gru_bih  = (const float*)d_in[14];
  const float* gru_bhh  = (const float*)d_in[15];
  const float* mlp_w1   = (const float*)d_in[16];
  const float* mlp_b1   = (const float*)d_in[17];
  const float* mlp_w2   = (const float*)d_in[18];
  const float* mlp_b2   = (const float*)d_in[19];
  const float* slots_mu = (const float*)d_in[20];
  const float* slots_ls = (const float*)d_in[21];

  float* out_slots = (float*)d_out;            // [32,16,256]
  float* out_attn  = out_slots + 131072;       // [32,4096,16]

  char* wsb = (char*)d_ws;
  size_t off = 0;
  short* xbf     = (short*)(wsb + off); off += 67108864;   // x bf16 [B,N,D]
  short* ux_part = (short*)(wsb + off); off += 33554432;   // [4096][16][256] bf16
  float* cs_part = (float*)(wsb + off); off += 262144;     // [4096][16]
  float* cs_red  = (float*)(wsb + off); off += 2048;       // [B*S]
  short* qk      = (short*)(wsb + off); off += 262144;     // [B*S][D] bf16
  short* uxr     = (short*)(wsb + off); off += 262144;     // reduced ux bf16
  short* MTb     = (short*)(wsb + off); off += 131072;     // Wq^T Wk bf16
  short* Mb      = (short*)(wsb + off); off += 393216;     // wih@Wv bf16 [768][256]
  float* gig     = (float*)(wsb + off); off += 3145728;    // [512][1536] f32
  float* slots   = (float*)(wsb + off); off += 524288;     // slots f32
  short* slotsb  = (short*)(wsb + off); off += 262144;     // slots bf16
  short* lnmb    = (short*)(wsb + off); off += 262144;     // LN_m bf16
  short* hb      = (short*)(wsb + off); off += 524288;     // mlp hidden bf16 [512][512]
  short* whhb    = (short*)(wsb + off); off += 393216;
  short* w1b     = (short*)(wsb + off); off += 262144;
  short* w2b     = (short*)(wsb + off); off += 262144;

  k_prep<<<704,256,0,stream>>>(Wq, Wk, gru_wih, Wv, gru_whh, mlp_w1, mlp_w2,
                               MTb, Mb, whhb, w1b, w2b);
  k_slotend<1><<<8,256,0,stream>>>(nullptr, nullptr, nullptr, slots_mu, slots_ls, noise,
                                   nullptr, slots, slotsb, ln_s_w, ln_s_b, MTb, qk);
  for (int it=0; it<3; ++it) {
    if (it==0)
      k3<1,0><<<4096,256,0,stream>>>(inputs, ln_in_w, ln_in_b, xbf, qk, token_w,
                                     ux_part, cs_part, out_attn);
    else if (it==1)
      k3<0,0><<<4096,256,0,stream>>>(inputs, ln_in_w, ln_in_b, xbf, qk, token_w,
                                     ux_part, cs_part, out_attn);
    else
      k3<0,1><<<4096,256,0,stream>>>(inputs, ln_in_w, ln_in_b, xbf, qk, token_w,
                                     ux_part, cs_part, out_attn);
    k_reduce<<<512,256,0,stream>>>(ux_part, cs_part, uxr, cs_red);
    k_gigh<<<dim3(24,8),256,0,stream>>>(uxr, slotsb, Mb, whhb, gru_bih, gru_bhh, gig);
    k_gates<<<128,256,0,stream>>>(gig, ln_m_w, ln_m_b, slots, lnmb);
    k_mlp1<<<dim3(8,8),256,0,stream>>>(lnmb, w1b, mlp_b1, hb);
    if (it<2)
      k_slotend<0><<<8,256,0,stream>>>(hb, w2b, mlp_b2, nullptr, nullptr, nullptr,
                                       slots, slots, slotsb, ln_s_w, ln_s_b, MTb, qk);
    else
      k_slotend<2><<<8,256,0,stream>>>(hb, w2b, mlp_b2, nullptr, nullptr, nullptr,
                                       slots, out_slots, slotsb, ln_s_w, ln_s_b, MTb, qk);
  }
  k_attn_norm<<<2048,256,0,stream>>>(out_attn, cs_red);
}

// Round 10
// 241.076 us; speedup vs baseline: 1.3698x; 1.1280x over previous
//
#include <hip/hip_runtime.h>
#include <hip/hip_bf16.h>
#include <math.h>

// SlotAttention on MI355X.
// Factorizations:
//   k,v never materialized:  qk = LN(slots) @ (Wq^T Wk);  logits = x·qk
//   updates feeds only the GRU input GEMM:  gi = uxr @ (wih·Wv)^T  (M precomputed)
//   token-normalization 1/(colsum+eps) commutes out of the P^T@X accumulation.
// R10: faithful revert of k3/reduce/partials to the R4 (241us) versions.
//   R6-R9 k3 variants (qkf-in-regs, group-split, 32-row, forced bounds) all
//   regressed to 77-80us/pass; R4's 4-group-per-block loop with cross-group
//   register prefetch + coalesced QKs LDS staging ran ~65us/pass. R8/R9 also
//   suffered compiler spills (VGPR capped at 40/48, +64MB scratch writes).
//   Only retained post-R4 change: attn written direct to out_attn + in-place
//   normalization (proven R6-R9, traffic-neutral).

#define EPS_ 1e-8f
#define LNEPS_ 1e-5f

typedef __attribute__((ext_vector_type(8))) short bf16x8;
typedef __attribute__((ext_vector_type(4))) float f32x4;
typedef __attribute__((ext_vector_type(4))) short s16x4;

static __device__ __forceinline__ short f2bf(float f) {
  __hip_bfloat16 h = __float2bfloat16(f);
  union { __hip_bfloat16 h; short s; } u; u.h = h; return u.s;
}
static __device__ __forceinline__ float4 ld4(const float* p){ return *(const float4*)p; }

// ---------------- prep: MT = Wq^T Wk, M = wih@Wv, bf16 casts ----------------
__global__ __launch_bounds__(256) void k_prep(
    const float* __restrict__ Wq, const float* __restrict__ Wk,
    const float* __restrict__ wih, const float* __restrict__ Wv,
    const float* __restrict__ whh, const float* __restrict__ w1, const float* __restrict__ w2,
    short* __restrict__ MTb, short* __restrict__ Mb, short* __restrict__ whhb,
    short* __restrict__ w1b, short* __restrict__ w2b) {
  int blk = blockIdx.x, t = threadIdx.x;
  if (blk < 64) {                 // MT[e][f] = sum_d Wq[d][f]*Wk[d][e]
    int e0 = blk*4;
    float a0=0,a1=0,a2=0,a3=0;
    for (int d=0; d<256; d++) {
      float qv = Wq[d*256 + t];
      a0 += qv*Wk[d*256+e0];   a1 += qv*Wk[d*256+e0+1];
      a2 += qv*Wk[d*256+e0+2]; a3 += qv*Wk[d*256+e0+3];
    }
    MTb[(e0  )*256+t]=f2bf(a0); MTb[(e0+1)*256+t]=f2bf(a1);
    MTb[(e0+2)*256+t]=f2bf(a2); MTb[(e0+3)*256+t]=f2bf(a3);
  } else if (blk < 256) {         // M[n][e] = sum_d wih[n][d]*Wv[d][e]
    int n0 = (blk-64)*4;
    float a0=0,a1=0,a2=0,a3=0;
    for (int d=0; d<256; d++) {
      float vv = Wv[d*256 + t];
      a0 += wih[(n0  )*256+d]*vv; a1 += wih[(n0+1)*256+d]*vv;
      a2 += wih[(n0+2)*256+d]*vv; a3 += wih[(n0+3)*256+d]*vv;
    }
    Mb[(size_t)(n0  )*256+t]=f2bf(a0); Mb[(size_t)(n0+1)*256+t]=f2bf(a1);
    Mb[(size_t)(n0+2)*256+t]=f2bf(a2); Mb[(size_t)(n0+3)*256+t]=f2bf(a3);
  } else {                        // casts: whh 49152, w1 32768, w2 32768 float4s
    int c = (blk-256)*256 + t;
    const float* src; short* dst;
    if (c < 49152) { src=whh; dst=whhb; }
    else if ((c-=49152) < 32768) { src=w1; dst=w1b; }
    else { c-=32768; src=w2; dst=w2b; }
    float4 v = ld4(src + (size_t)c*4);
    short4 o; o.x=f2bf(v.x); o.y=f2bf(v.y); o.z=f2bf(v.z); o.w=f2bf(v.w);
    *(short4*)(dst + (size_t)c*4) = o;
  }
}

// ---------------- fused attention pass (+optional LN-of-inputs) ----------------
// grid = B*16 blocks (256 token-rows each, 4 groups of 64), 256 threads = 4 waves.
// R4-proven: cross-group register prefetch keeps memory busy under compute.
template<int LNIN, int WATTN>
__global__ __launch_bounds__(256) void k3(
    const float* __restrict__ inputs, const float* __restrict__ lnw, const float* __restrict__ lnb,
    short* __restrict__ xbf, const short* __restrict__ qk, const float* __restrict__ twg,
    float* __restrict__ ux_part, float* __restrict__ colsum_part, float* __restrict__ attn_un) {
  __shared__ short Xs[64*264];
  __shared__ short QKs[16*264];
  __shared__ short Pt[16*72];
  __shared__ float tws[64];
  __shared__ float cs[16];
  __shared__ float lnwb[512];
  const int t = threadIdx.x;
  const int b = blockIdx.x >> 4;
  const int n0 = (blockIdx.x & 15) * 256;
  const int lane = t & 63, w = t >> 6, l15 = lane & 15, lg = lane >> 4;
  #pragma unroll
  for (int i=0;i<2;i++){
    int cid = t + i*256;
    int row = cid>>5, ck = cid&31;
    *(uint4*)&QKs[row*264 + ck*8] = *(const uint4*)&qk[((size_t)(b*16+row))*256 + ck*8];
  }
  if (LNIN){
    if (t < 64)       *(float4*)&lnwb[t*4]           = ld4(lnw + t*4);
    else if (t < 128) *(float4*)&lnwb[256+(t-64)*4]  = ld4(lnb + (t-64)*4);
  }
  if (t<16) cs[t]=0.f;
  f32x4 uacc[4] = {};
  for (int g=0; g<4; ++g) {
    __syncthreads();
    const size_t rowbase = (size_t)b*4096 + n0 + g*64;
    if (LNIN) {
      const float* ing = inputs + rowbase*256;
      const int r = t>>2, c = t&3;
      float4 vv[16];
      #pragma unroll
      for (int k=0;k<16;k++) vv[k] = ld4(ing + r*256 + (c+4*k)*4);
      float s=0.f, sq=0.f;
      #pragma unroll
      for (int k=0;k<16;k++){
        s  += vv[k].x+vv[k].y+vv[k].z+vv[k].w;
        sq += vv[k].x*vv[k].x+vv[k].y*vv[k].y+vv[k].z*vv[k].z+vv[k].w*vv[k].w;
      }
      s += __shfl_xor(s,1);  s += __shfl_xor(s,2);
      sq += __shfl_xor(sq,1); sq += __shfl_xor(sq,2);
      float mean = s*(1.f/256.f);
      float rstd = rsqrtf(sq*(1.f/256.f) - mean*mean + LNEPS_);
      short* xw = xbf + rowbase*256;
      #pragma unroll
      for (int k=0;k<16;k++){
        int d0 = (c+4*k)*4;
        float4 wv = *(float4*)&lnwb[d0];
        float4 bv = *(float4*)&lnwb[256+d0];
        s16x4 pk;
        pk[0]=f2bf((vv[k].x-mean)*rstd*wv.x+bv.x);
        pk[1]=f2bf((vv[k].y-mean)*rstd*wv.y+bv.y);
        pk[2]=f2bf((vv[k].z-mean)*rstd*wv.z+bv.z);
        pk[3]=f2bf((vv[k].w-mean)*rstd*wv.w+bv.w);
        *(s16x4*)&Xs[r*264 + d0] = pk;
        *(s16x4*)&xw[r*256 + d0] = pk;
      }
    } else {
      const short* xg = xbf + rowbase*256;
      #pragma unroll
      for (int r8=0;r8<8;r8++){
        int row = r8*8 + (t>>5), ck = t&31;
        *(uint4*)&Xs[row*264 + ck*8] = *(const uint4*)&xg[(size_t)row*256 + ck*8];
      }
    }
    if (t<64) tws[t] = fmaxf(twg[rowbase + t], 0.f);
    __syncthreads();
    // GEMM1: D[row][s] = x_row . qk_s
    f32x4 acc = {0.f,0.f,0.f,0.f};
    #pragma unroll
    for (int kk=0;kk<8;kk++){
      bf16x8 af  = *(const bf16x8*)&Xs[(w*16+l15)*264 + kk*32 + lg*8];
      bf16x8 bfr = *(const bf16x8*)&QKs[l15*264 + kk*32 + lg*8];
      acc = __builtin_amdgcn_mfma_f32_16x16x32_bf16(af, bfr, acc, 0,0,0);
    }
    float a4[4];
    #pragma unroll
    for (int q=0;q<4;q++){
      float v = acc[q]*0.0625f;          // * D^-0.5
      float m = v;
      #pragma unroll
      for (int d=1; d<16; d<<=1) m = fmaxf(m, __shfl_xor(m, d, 16));
      float e = __expf(v-m);
      float se = e;
      #pragma unroll
      for (int d=1; d<16; d<<=1) se += __shfl_xor(se, d, 16);
      int row = w*16 + lg*4 + q;
      float a = (e/se)*tws[row];
      a4[q] = a;
      if (WATTN)
        attn_un[(rowbase + row)*16 + l15] = a;
    }
    float psum = a4[0]+a4[1]+a4[2]+a4[3];
    psum += __shfl_xor(psum, 16);
    psum += __shfl_xor(psum, 32);
    if (lane<16) atomicAdd(&cs[l15], psum);
    s16x4 pk; pk[0]=f2bf(a4[0]); pk[1]=f2bf(a4[1]); pk[2]=f2bf(a4[2]); pk[3]=f2bf(a4[3]);
    *(s16x4*)&Pt[l15*72 + w*16 + lg*4] = pk;
    __syncthreads();
    // GEMM2: ux[s][e] += P^T @ X ; wave w owns e-cols [w*64, w*64+64)
    #pragma unroll
    for (int kk=0;kk<2;kk++){
      bf16x8 a2 = *(const bf16x8*)&Pt[l15*72 + kk*32 + lg*8];
      #pragma unroll
      for (int tt=0;tt<4;tt++){
        int col = w*64 + tt*16 + l15;
        int rbv = kk*32 + lg*8;
        bf16x8 b2;
        #pragma unroll
        for (int j=0;j<8;j++) b2[j] = Xs[(rbv+j)*264 + col];
        uacc[tt] = __builtin_amdgcn_mfma_f32_16x16x32_bf16(a2, b2, uacc[tt], 0,0,0);
      }
    }
  }
  __syncthreads();
  if (t<16) colsum_part[blockIdx.x*16 + t] = cs[t];
  #pragma unroll
  for (int tt=0;tt<4;tt++){
    #pragma unroll
    for (int q=0;q<4;q++)
      ux_part[(size_t)blockIdx.x*4096 + (lg*4+q)*256 + w*64 + tt*16 + l15] = uacc[tt][q];
  }
}

// ---------------- reduce ux partials (+fold 1/(colsum+eps)) -> bf16 ----------------
__global__ __launch_bounds__(256) void k_reduce(const float* __restrict__ uxp,
    const float* __restrict__ csp, short* __restrict__ uxr, float* __restrict__ csr) {
  int r = blockIdx.x;          // b*16+s
  int b = r>>4, s = r&15;
  int t = threadIdx.x;
  float cs = 0.f;
  #pragma unroll
  for (int k=0;k<16;k++) cs += csp[((b<<4)+k)*16 + s];
  float u = 0.f;
  #pragma unroll
  for (int k=0;k<16;k++) u += uxp[(size_t)((b<<4)+k)*4096 + s*256 + t];
  uxr[(size_t)r*256+t] = f2bf(u/(cs+EPS_));
  if (t==0) csr[r] = cs;
}

// ---------------- gi|gh GEMM: gig[row][0:768]=uxr@M^T+bih, [768:1536]=slotsb@whh^T+bhh ----
__global__ __launch_bounds__(256) void k_gigh(
    const short* __restrict__ uxr, const short* __restrict__ slotsb,
    const short* __restrict__ Mb, const short* __restrict__ whhb,
    const float* __restrict__ bih, const float* __restrict__ bhh,
    float* __restrict__ gig) {
  __shared__ short As[64*40];
  __shared__ short Ws[64*40];
  const int t=threadIdx.x, bn=blockIdx.x, bm=blockIdx.y;
  const short* A; const short* W; const float* bias; int wo;
  if (bn<12) { A=uxr;    W=Mb   + (size_t)bn*64*256;      bias=bih; wo=bn*64; }
  else       { A=slotsb; W=whhb + (size_t)(bn-12)*64*256; bias=bhh; wo=(bn-12)*64; }
  const int w=t>>6, lane=t&63, l15=lane&15, lg=lane>>4;
  f32x4 acc[4]={};
  for (int k0=0;k0<256;k0+=32){
    __syncthreads();
    *(uint4*)&As[(t>>2)*40+(t&3)*8] = *(const uint4*)&A[(size_t)(bm*64+(t>>2))*256 + k0 + (t&3)*8];
    *(uint4*)&Ws[(t>>2)*40+(t&3)*8] = *(const uint4*)&W[(size_t)(t>>2)*256 + k0 + (t&3)*8];
    __syncthreads();
    bf16x8 af = *(const bf16x8*)&As[(w*16+l15)*40+lg*8];
    #pragma unroll
    for (int ct=0;ct<4;ct++){
      bf16x8 bfr = *(const bf16x8*)&Ws[(ct*16+l15)*40+lg*8];
      acc[ct]=__builtin_amdgcn_mfma_f32_16x16x32_bf16(af,bfr,acc[ct],0,0,0);
    }
  }
  #pragma unroll
  for (int ct=0;ct<4;ct++){
    float bv = bias[wo + ct*16 + l15];
    #pragma unroll
    for (int q=0;q<4;q++){
      int row = bm*64 + w*16 + lg*4 + q;
      gig[(size_t)row*1536 + bn*64 + ct*16 + l15] = acc[ct][q] + bv;
    }
  }
}

// ---------------- MLP1: hb = gelu(lnmb @ w1^T + b1), bf16 ----------------
__global__ __launch_bounds__(256) void k_mlp1(
    const short* __restrict__ lnmb, const short* __restrict__ w1b,
    const float* __restrict__ b1, short* __restrict__ hb) {
  __shared__ short As[64*40];
  __shared__ short Ws[64*40];
  const int t=threadIdx.x, bn=blockIdx.x, bm=blockIdx.y;
  const int w=t>>6, lane=t&63, l15=lane&15, lg=lane>>4;
  f32x4 acc[4]={};
  for (int k0=0;k0<256;k0+=32){
    __syncthreads();
    *(uint4*)&As[(t>>2)*40+(t&3)*8] = *(const uint4*)&lnmb[(size_t)(bm*64+(t>>2))*256 + k0 + (t&3)*8];
    *(uint4*)&Ws[(t>>2)*40+(t&3)*8] = *(const uint4*)&w1b[(size_t)(bn*64+(t>>2))*256 + k0 + (t&3)*8];
    __syncthreads();
    bf16x8 af = *(const bf16x8*)&As[(w*16+l15)*40+lg*8];
    #pragma unroll
    for (int ct=0;ct<4;ct++){
      bf16x8 bfr = *(const bf16x8*)&Ws[(ct*16+l15)*40+lg*8];
      acc[ct]=__builtin_amdgcn_mfma_f32_16x16x32_bf16(af,bfr,acc[ct],0,0,0);
    }
  }
  #pragma unroll
  for (int ct=0;ct<4;ct++){
    float bv = b1[bn*64 + ct*16 + l15];
    #pragma unroll
    for (int q=0;q<4;q++){
      int row = bm*64 + w*16 + lg*4 + q;
      float v = acc[ct][q] + bv;
      v = 0.5f*v*(1.f+erff(v*0.70710678118654752f));
      hb[(size_t)row*512 + bn*64 + ct*16 + l15] = f2bf(v);
    }
  }
}

// ---------------- GRU gates + LayerNorm(ln_m), wave per row ----------------
__global__ __launch_bounds__(256) void k_gates(const float* __restrict__ gig,
    const float* __restrict__ lw, const float* __restrict__ lb,
    float* __restrict__ slots, short* __restrict__ lnmb) {
  int row  = blockIdx.x*4 + (threadIdx.x>>6);
  int lane = threadIdx.x & 63;
  const float* gi = gig + (size_t)row*1536 + lane*4;
  float4 ir = ld4(gi), iz = ld4(gi+256), inn = ld4(gi+512);
  float4 hr = ld4(gi+768), hz = ld4(gi+1024), hn = ld4(gi+1280);
  float* sp = slots + (size_t)row*256 + lane*4;
  float4 h = ld4(sp);
  float hp[4];
  {
    float r0 = 1.f/(1.f+__expf(-(ir.x+hr.x))); float z0 = 1.f/(1.f+__expf(-(iz.x+hz.x)));
    hp[0] = (1.f-z0)*tanhf(inn.x + r0*hn.x) + z0*h.x;
    float r1 = 1.f/(1.f+__expf(-(ir.y+hr.y))); float z1 = 1.f/(1.f+__expf(-(iz.y+hz.y)));
    hp[1] = (1.f-z1)*tanhf(inn.y + r1*hn.y) + z1*h.y;
    float r2 = 1.f/(1.f+__expf(-(ir.z+hr.z))); float z2 = 1.f/(1.f+__expf(-(iz.z+hz.z)));
    hp[2] = (1.f-z2)*tanhf(inn.z + r2*hn.z) + z2*h.z;
    float r3 = 1.f/(1.f+__expf(-(ir.w+hr.w))); float z3 = 1.f/(1.f+__expf(-(iz.w+hz.w)));
    hp[3] = (1.f-z3)*tanhf(inn.w + r3*hn.w) + z3*h.w;
  }
  float s = hp[0]+hp[1]+hp[2]+hp[3];
  float sq = hp[0]*hp[0]+hp[1]*hp[1]+hp[2]*hp[2]+hp[3]*hp[3];
  #pragma unroll
  for (int d=1; d<64; d<<=1) { s += __shfl_xor(s,d); sq += __shfl_xor(sq,d); }
  float mean = s*(1.f/256.f);
  float rstd = rsqrtf(sq*(1.f/256.f) - mean*mean + LNEPS_);
  float4 wv = ld4(lw+lane*4), bv = ld4(lb+lane*4);
  *(float4*)sp = make_float4(hp[0],hp[1],hp[2],hp[3]);
  short4 o;
  o.x = f2bf((hp[0]-mean)*rstd*wv.x+bv.x);
  o.y = f2bf((hp[1]-mean)*rstd*wv.y+bv.y);
  o.z = f2bf((hp[2]-mean)*rstd*wv.z+bv.z);
  o.w = f2bf((hp[3]-mean)*rstd*wv.w+bv.w);
  *(short4*)(lnmb + (size_t)row*256 + lane*4) = o;
}

// ---------------- slot tail: [MLP2+res | slots-init] + LN_s + qk-GEMM ----------------
// MODE 0: v = hb@w2^T+b2+res(slots), write slots f32+slotsb, LN_s -> qk
// MODE 1: v = mu + sigma*noise (init), write slots f32+slotsb, LN_s -> qk
// MODE 2: v = hb@w2^T+b2+res(slots), write sout (=out_slots) only
template<int MODE>
__global__ __launch_bounds__(256) void k_slotend(
    const short* __restrict__ hb, const short* __restrict__ w2b, const float* __restrict__ b2,
    const float* __restrict__ mu, const float* __restrict__ ls, const float* __restrict__ noise,
    const float* __restrict__ res, float* __restrict__ sout, short* __restrict__ slotsb,
    const float* __restrict__ lnsw, const float* __restrict__ lnsb,
    const short* __restrict__ MTb, short* __restrict__ qk) {
  __shared__ short As[64*40];
  __shared__ short Ws[256*40];
  __shared__ short lnS[64*264];
  const int t=threadIdx.x, bm=blockIdx.x;
  const int w=t>>6, lane=t&63, l15=lane&15, lg=lane>>4;
  float v[16][4];
  if (MODE==1) {
    #pragma unroll
    for (int ct=0;ct<16;ct++){
      int col = ct*16+l15;
      float m = mu[col], sg = fmaxf(__expf(ls[col]),1e-6f);
      #pragma unroll
      for (int q=0;q<4;q++){
        int row = bm*64 + w*16 + lg*4 + q;
        v[ct][q] = m + sg*noise[(size_t)row*256+col];
      }
    }
  } else {
    f32x4 acc[16]={};
    for (int k0=0;k0<512;k0+=32){
      __syncthreads();
      *(uint4*)&As[(t>>2)*40+(t&3)*8] = *(const uint4*)&hb[(size_t)(bm*64+(t>>2))*512 + k0 + (t&3)*8];
      // stage 256 rows x 32 k of w2b: 1024 uint4 -> 4 iterations (NOT 8: R3 OOB lesson)
      #pragma unroll
      for (int i=0;i<4;i++){ int idx=t+i*256;
        *(uint4*)&Ws[(idx>>2)*40+(idx&3)*8] = *(const uint4*)&w2b[(size_t)(idx>>2)*512 + k0 + (idx&3)*8]; }
      __syncthreads();
      bf16x8 af = *(const bf16x8*)&As[(w*16+l15)*40+lg*8];
      #pragma unroll
      for (int ct=0;ct<16;ct++){
        bf16x8 bfr = *(const bf16x8*)&Ws[(ct*16+l15)*40+lg*8];
        acc[ct]=__builtin_amdgcn_mfma_f32_16x16x32_bf16(af,bfr,acc[ct],0,0,0);
      }
    }
    #pragma unroll
    for (int ct=0;ct<16;ct++){
      int col = ct*16+l15;
      float bv = b2[col];
      #pragma unroll
      for (int q=0;q<4;q++){
        int row = bm*64 + w*16 + lg*4 + q;
        v[ct][q] = acc[ct][q] + bv + res[(size_t)row*256+col];
      }
    }
  }
  float s[4]={0,0,0,0}, sq[4]={0,0,0,0};
  #pragma unroll
  for (int ct=0;ct<16;ct++)
    #pragma unroll
    for (int q=0;q<4;q++){ s[q]+=v[ct][q]; sq[q]+=v[ct][q]*v[ct][q]; }
  #pragma unroll
  for (int q=0;q<4;q++){
    #pragma unroll
    for (int d=1; d<16; d<<=1){ s[q]+=__shfl_xor(s[q],d,16); sq[q]+=__shfl_xor(sq[q],d,16); }
  }
  #pragma unroll
  for (int ct=0;ct<16;ct++){
    int col = ct*16+l15;
    float lw = (MODE!=2) ? lnsw[col] : 0.f;
    float lb = (MODE!=2) ? lnsb[col] : 0.f;
    #pragma unroll
    for (int q=0;q<4;q++){
      int row = bm*64 + w*16 + lg*4 + q;
      sout[(size_t)row*256+col] = v[ct][q];
      if (MODE!=2){
        float mean = s[q]*(1.f/256.f);
        float rstd = rsqrtf(sq[q]*(1.f/256.f)-mean*mean+LNEPS_);
        slotsb[(size_t)row*256+col] = f2bf(v[ct][q]);
        lnS[(w*16+lg*4+q)*264 + col] = f2bf((v[ct][q]-mean)*rstd*lw+lb);
      }
    }
  }
  if (MODE!=2){
    f32x4 qa[16]={};
    for (int k0=0;k0<256;k0+=32){
      __syncthreads();
      #pragma unroll
      for (int i=0;i<4;i++){ int idx=t+i*256;   // 256 rows x 32 k = 1024 uint4
        *(uint4*)&Ws[(idx>>2)*40+(idx&3)*8] = *(const uint4*)&MTb[(size_t)(idx>>2)*256 + k0 + (idx&3)*8]; }
      __syncthreads();
      bf16x8 af = *(const bf16x8*)&lnS[(w*16+l15)*264 + k0 + lg*8];
      #pragma unroll
      for (int ct=0;ct<16;ct++){
        bf16x8 bfr = *(const bf16x8*)&Ws[(ct*16+l15)*40+lg*8];
        qa[ct]=__builtin_amdgcn_mfma_f32_16x16x32_bf16(af,bfr,qa[ct],0,0,0);
      }
    }
    #pragma unroll
    for (int ct=0;ct<16;ct++)
      #pragma unroll
      for (int q=0;q<4;q++)
        qk[(size_t)(bm*64+w*16+lg*4+q)*256 + ct*16+l15] = f2bf(qa[ct][q]);
  }
}

// ---------------- final attn normalization (in place on d_out) ----------------
__global__ __launch_bounds__(256) void k_attn_norm(float* __restrict__ au,
    const float* __restrict__ cs) {
  size_t i = ((size_t)blockIdx.x*256 + threadIdx.x)*4;
  float4 v = ld4(au + i);
  int s = (int)(i & 15);
  size_t b = i >> 16;           // 4096*16 elems per batch
  const float* c = cs + b*16 + s;
  float4 o;
  o.x = v.x/(c[0]+EPS_); o.y = v.y/(c[1]+EPS_);
  o.z = v.z/(c[2]+EPS_); o.w = v.w/(c[3]+EPS_);
  *(float4*)(au + i) = o;
}

extern "C" void kernel_launch(void* const* d_in, const int* in_sizes, int n_in,
                              void* d_out, int out_size, void* d_ws, size_t ws_size,
                              hipStream_t stream) {
  const float* inputs   = (const float*)d_in[0];
  const float* token_w  = (const float*)d_in[1];
  const float* noise    = (const float*)d_in[2];
  const float* ln_in_w  = (const float*)d_in[3];
  const float* ln_in_b  = (const float*)d_in[4];
  const float* ln_s_w   = (const float*)d_in[5];
  const float* ln_s_b   = (const float*)d_in[6];
  const float* ln_m_w   = (const float*)d_in[7];
  const float* ln_m_b   = (const float*)d_in[8];
  const float* Wk       = (const float*)d_in[9];
  const float* Wv       = (const float*)d_in[10];
  const float* Wq       = (const float*)d_in[11];
  const float* gru_wih  = (const float*)d_in[12];
  const float* gru_whh  = (const float*)d_in[13];
  const float* gru_bih  = (const float*)d_in[14];
  const float* gru_bhh  = (const float*)d_in[15];
  const float* mlp_w1   = (const float*)d_in[16];
  const float* mlp_b1   = (const float*)d_in[17];
  const float* mlp_w2   = (const float*)d_in[18];
  const float* mlp_b2   = (const float*)d_in[19];
  const float* slots_mu = (const float*)d_in[20];
  const float* slots_ls = (const float*)d_in[21];

  float* out_slots = (float*)d_out;            // [32,16,256]
  float* out_attn  = out_slots + 131072;       // [32,4096,16]

  char* wsb = (char*)d_ws;
  size_t off = 0;
  short* xbf     = (short*)(wsb + off); off += 67108864;   // x bf16 [B,N,D]
  float* ux_part = (float*)(wsb + off); off += 8388608;    // [512][16][256] f32
  float* cs_part = (float*)(wsb + off); off += 32768;      // [512][16]
  float* cs_red  = (float*)(wsb + off); off += 2048;       // [B*S]
  short* qk      = (short*)(wsb + off); off += 262144;     // [B*S][D] bf16
  short* uxr     = (short*)(wsb + off); off += 262144;     // reduced ux bf16
  short* MTb     = (short*)(wsb + off); off += 131072;     // Wq^T Wk bf16
  short* Mb      = (short*)(wsb + off); off += 393216;     // wih@Wv bf16 [768][256]
  float* gig     = (float*)(wsb + off); off += 3145728;    // [512][1536] f32
  float* slots   = (float*)(wsb + off); off += 524288;     // slots f32
  short* slotsb  = (short*)(wsb + off); off += 262144;     // slots bf16
  short* lnmb    = (short*)(wsb + off); off += 262144;     // LN_m bf16
  short* hb      = (short*)(wsb + off); off += 524288;     // mlp hidden bf16 [512][512]
  short* whhb    = (short*)(wsb + off); off += 393216;
  short* w1b     = (short*)(wsb + off); off += 262144;
  short* w2b     = (short*)(wsb + off); off += 262144;

  k_prep<<<704,256,0,stream>>>(Wq, Wk, gru_wih, Wv, gru_whh, mlp_w1, mlp_w2,
                               MTb, Mb, whhb, w1b, w2b);
  k_slotend<1><<<8,256,0,stream>>>(nullptr, nullptr, nullptr, slots_mu, slots_ls, noise,
                                   nullptr, slots, slotsb, ln_s_w, ln_s_b, MTb, qk);
  for (int it=0; it<3; ++it) {
    if (it==0)
      k3<1,0><<<512,256,0,stream>>>(inputs, ln_in_w, ln_in_b, xbf, qk, token_w,
                                    ux_part, cs_part, out_attn);
    else if (it==1)
      k3<0,0><<<512,256,0,stream>>>(inputs, ln_in_w, ln_in_b, xbf, qk, token_w,
                                    ux_part, cs_part, out_attn);
    else
      k3<0,1><<<512,256,0,stream>>>(inputs, ln_in_w, ln_in_b, xbf, qk, token_w,
                                    ux_part, cs_part, out_attn);
    k_reduce<<<512,256,0,stream>>>(ux_part, cs_part, uxr, cs_red);
    k_gigh<<<dim3(24,8),256,0,stream>>>(uxr, slotsb, Mb, whhb, gru_bih, gru_bhh, gig);
    k_gates<<<128,256,0,stream>>>(gig, ln_m_w, ln_m_b, slots, lnmb);
    k_mlp1<<<dim3(8,8),256,0,stream>>>(lnmb, w1b, mlp_b1, hb);
    if (it<2)
      k_slotend<0><<<8,256,0,stream>>>(hb, w2b, mlp_b2, nullptr, nullptr, nullptr,
                                       slots, slots, slotsb, ln_s_w, ln_s_b, MTb, qk);
    else
      k_slotend<2><<<8,256,0,stream>>>(hb, w2b, mlp_b2, nullptr, nullptr, nullptr,
                                       slots, out_slots, slotsb, ln_s_w, ln_s_b, MTb, qk);
  }
  k_attn_norm<<<2048,256,0,stream>>>(out_attn, cs_red);
}